// Round 5
// baseline (363.002 us; speedup 1.0000x reference)
//
#include <hip/hip_runtime.h>
#include <math.h>

// SpectrumHead: rfft2(512x512) magnitude -> radial/angular histogram -> linear proj.
// B=64, C=3, H=512, W=512, W2=257 (padded to 272), K_BINS=16, O_BINS=8, proj=64.
//
// Pass 0: bin-code table binsNat[row][j] = rb | ob<<4 (natural row order).
// Pass 1: row real-FFTs, 2 rows packed per complex 512-pt DIT FFT (LDS twiddles,
//         XOR-swizzled LDS), write [512][272] complex intermediate.
// Pass 2: column FFTs via THREE-step 512 = 8x8x8 register FFT: 8 points/thread
//         (z[8] = 16 VGPR), 64 threads/column, 4 columns/block, two small LDS
//         transposes in one shared 18.4 KB buffer. High occupancy (launch_bounds
//         256,6) hides LDS/barrier latency that bounded the 32x16 version.
// Pass 3: reduce tile-partials per batch, normalize, h @ W.T + b.

#define TPB 256
#define PI_F 3.14159265358979323846f
#define TWO_PI_F 6.28318530717958647692f
#define W2 257
#define W2P 272            // padded row stride in float2
#define NTILE 65           // ceil(257/4) columns tiles (4 cols per block)
#define CSTRIDE 576        // per-column float2 stride of shared transpose buffer
#define SW(p) ((p) ^ (((p) >> 5) & 15))   // pass1 LDS anti-conflict swizzle

__device__ __forceinline__ int brev9(int p) { return (int)(__brev((unsigned)p) >> 23); }

// exp(-2*pi*i*k/32), k = 0..15
static constexpr float TW32_RE[16] = {
   1.0f,          0.98078528f,  0.92387953f,  0.83146961f,
   0.70710678f,   0.55557023f,  0.38268343f,  0.19509032f,
   0.0f,         -0.19509032f, -0.38268343f, -0.55557023f,
  -0.70710678f,  -0.83146961f, -0.92387953f, -0.98078528f };
static constexpr float TW32_IM[16] = {
  -0.0f,         -0.19509032f, -0.38268343f, -0.55557023f,
  -0.70710678f,  -0.83146961f, -0.92387953f, -0.98078528f,
  -1.0f,         -0.98078528f, -0.92387953f, -0.83146961f,
  -0.70710678f,  -0.55557023f, -0.38268343f, -0.19509032f };

static constexpr int BR3[8] = {0,4,2,6,1,5,3,7};

// In-register DIT FFT, N = 2^LOGN (LOGN <= 5), twiddles from TW32 (k = jj<<(4-s)).
// Input must be bit-rev permuted; output natural order. Fully unrolled -> VGPRs.
template <int LOGN>
__device__ __forceinline__ void fft_reg(float2* z) {
  const int N = 1 << LOGN;
  #pragma unroll
  for (int s = 0; s < LOGN; ++s) {
    const int h = 1 << s;
    #pragma unroll
    for (int g0 = 0; g0 < N; g0 += 2 * h) {
      #pragma unroll
      for (int jj = 0; jj < h; ++jj) {
        const int k = jj << (4 - s);
        const float wr = TW32_RE[k], wi = TW32_IM[k];
        float2 a = z[g0 + jj];
        float2 b = z[g0 + jj + h];
        float tr = b.x * wr - b.y * wi;
        float ti = b.x * wi + b.y * wr;
        z[g0 + jj]     = make_float2(a.x + tr, a.y + ti);
        z[g0 + jj + h] = make_float2(a.x - tr, a.y - ti);
      }
    }
  }
}

__device__ __forceinline__ void get_bins(int i, int j, int& rb, int& ob) {
  float yy = -1.0f + (float)i * (2.0f / 511.0f);
  float xx = (float)j * (1.0f / 256.0f);
  float rr = sqrtf(yy * yy + xx * xx);
  rr = fminf(rr, 1.0f - 1e-8f);
  float th = atan2f(yy, xx + 1e-9f) + 1.57079632679489662f;
  rb = (int)(rr * 16.0f);
  rb = rb < 0 ? 0 : (rb > 15 ? 15 : rb);
  ob = (int)((th / PI_F) * 8.0f);
  ob = ob < 0 ? 0 : (ob > 7 ? 7 : ob);
}

// Pass 0: bin table, natural row order. blockIdx.x = row i.
__global__ __launch_bounds__(TPB) void pass0_kernel(unsigned char* __restrict__ binsNat) {
  int i = blockIdx.x;
  #pragma unroll
  for (int e = 0; e < 2; e++) {
    int j = threadIdx.x + e * 256;
    if (j < W2) {
      int rb, ob;
      get_bins(i, j, rb, ob);
      binsNat[i * W2P + j] = (unsigned char)(rb | (ob << 4));
    }
  }
}

// Pass 1: blockIdx.x = ic_local*256 + rpair. Two real rows -> one complex DIT FFT.
__global__ __launch_bounds__(TPB) void pass1_kernel(
    const float* __restrict__ x, float2* __restrict__ F, int ic0) {
  __shared__ float2 buf[512];
  __shared__ float2 tw[256];
  int t = threadIdx.x;
  int bid = blockIdx.x;
  int rpair = bid & 255;
  int ic_local = bid >> 8;
  const float* row0 = x + (((size_t)(ic0 + ic_local)) * 512 + (size_t)rpair * 2) * 512;
  const float* row1 = row0 + 512;

  {
    float sn, cs;
    sincosf(-TWO_PI_F * (float)t * (1.0f / 512.0f), &sn, &cs);
    tw[t] = make_float2(cs, sn);
  }

  #pragma unroll
  for (int e = 0; e < 2; e++) {
    int i = t + e * 256;
    int dst = brev9(i);
    buf[SW(dst)] = make_float2(row0[i], row1[i]);
  }
  __syncthreads();

  #pragma unroll
  for (int s = 0; s < 9; s++) {
    int h = 1 << s;
    int jj = t & (h - 1);
    int idx = ((t >> s) << (s + 1)) + jj;
    float2 w = tw[jj << (8 - s)];
    float2 a = buf[SW(idx)];
    float2 b = buf[SW(idx + h)];
    float2 wb = make_float2(b.x * w.x - b.y * w.y, b.x * w.y + b.y * w.x);
    buf[SW(idx)]     = make_float2(a.x + wb.x, a.y + wb.y);
    buf[SW(idx + h)] = make_float2(a.x - wb.x, a.y - wb.y);
    __syncthreads();
  }

  float2* out0 = F + ((size_t)ic_local * 512 + (size_t)rpair * 2) * W2P;
  float2* out1 = out0 + W2P;
  int k = t;
  int km = (512 - k) & 511;
  float2 zk = buf[SW(k)];
  float2 zm = buf[SW(km)];
  out0[k] = make_float2(0.5f * (zk.x + zm.x), 0.5f * (zk.y - zm.y));
  out1[k] = make_float2(0.5f * (zk.y + zm.y), -0.5f * (zk.x - zm.x));
  if (t == 0) {
    float2 z = buf[SW(256)];
    out0[256] = make_float2(z.x, 0.0f);
    out1[256] = make_float2(z.y, 0.0f);
  }
}

// Pass 2: blockIdx.x = b_local*NTILE + tile. 4 columns/block, 8x8x8 reg FFT.
// Thread t: col = t&3, u = t>>2 (0..63).
//   step 1: z[m] = f[u + 64m]; FFT_8 over m -> A_u[k3]; twiddle W_512^(u k3).
//   LDS L1[u][k3] (XOR swizzle)  -> step-2 thread (g1 = u'&7, k3 = u'>>3):
//   r[g2] = B[g1+8g2][k3]; FFT_8 -> C[K2]; twiddle W_64^(g1 K2).
//   LDS L2[k3][K2][g1] (pad 9)   -> step-3 thread (k3f = u''>>3, K2f = u''&7):
//   s[g1]; FFT_8 -> X[k3f + 8*K2f + 64*K1]; magnitude accumulate over channels.
__global__ __launch_bounds__(TPB, 6) void pass2_kernel(
    const float2* __restrict__ F, const unsigned char* __restrict__ binsNat,
    float* __restrict__ partial, int b0) {
  __shared__ float2 xbuf[4 * CSTRIDE];   // 18.4 KB, L1 and L2 time-share it
  __shared__ float2 tw512[512];          // exp(-2pi i k/512)
  __shared__ float hist[24];
  int t = threadIdx.x;
  int tile = blockIdx.x % NTILE;
  int b_local = blockIdx.x / NTILE;
  int col = t & 3;
  int u = t >> 2;                  // 0..63
  int j = tile * 4 + col;
  bool jvalid = (j < W2);
  float2* cb = xbuf + col * CSTRIDE;

  {
    float sn, cs;
    sincosf(-TWO_PI_F * (float)t * (1.0f / 512.0f), &sn, &cs);
    tw512[t] = make_float2(cs, sn);
    sincosf(-TWO_PI_F * (float)(t + 256) * (1.0f / 512.0f), &sn, &cs);
    tw512[t + 256] = make_float2(cs, sn);
  }
  if (t < 24) hist[t] = 0.0f;
  __syncthreads();

  const int g1 = u & 7, k3r = u >> 3;    // step-2 role
  const int k3f = u >> 3, K2f = u & 7;   // step-3 role

  const float2* Fb = F + (size_t)(b_local * 3) * (512 * W2P);

  float mag[8];
  #pragma unroll
  for (int q = 0; q < 8; ++q) mag[q] = 0.0f;

  for (int c = 0; c < 3; ++c) {
    // ---- step 1: 8-pt FFT over m (rows u + 64m), twiddle W_512^(u*k3) ----
    const float2* colp = Fb + (size_t)c * (512 * W2P) + (size_t)u * W2P + j;
    float2 z[8];
    #pragma unroll
    for (int m = 0; m < 8; ++m) {
      float2 v = make_float2(0.0f, 0.0f);
      if (jvalid) v = colp[(size_t)m * (64 * W2P)];
      z[BR3[m]] = v;
    }
    fft_reg<3>(z);                       // z[k3] = A_u[k3]
    #pragma unroll
    for (int k3 = 0; k3 < 8; ++k3) {
      float2 w = tw512[u * k3];
      float2 v = z[k3];
      z[k3] = make_float2(v.x * w.x - v.y * w.y, v.x * w.y + v.y * w.x);
    }
    __syncthreads();                     // prev channel's L2 reads complete
    #pragma unroll
    for (int k3 = 0; k3 < 8; ++k3)
      cb[u * 8 + (k3 ^ (u & 7))] = z[k3];     // L1[u][k3], XOR swizzle
    __syncthreads();

    // ---- step 2: 8-pt FFT over g2, twiddle W_64^(g1*K2) ----
    float2 r[8];
    #pragma unroll
    for (int g2 = 0; g2 < 8; ++g2)
      r[BR3[g2]] = cb[(g1 + 8 * g2) * 8 + (k3r ^ g1)];
    fft_reg<3>(r);                       // r[K2] = C[g1][k3r][K2]
    #pragma unroll
    for (int K2 = 0; K2 < 8; ++K2) {
      float2 w = tw512[(g1 * K2) << 3];  // W_64^(g1 K2) = W_512^(8 g1 K2)
      float2 v = r[K2];
      r[K2] = make_float2(v.x * w.x - v.y * w.y, v.x * w.y + v.y * w.x);
    }
    __syncthreads();                     // L1 reads complete before overwrite
    #pragma unroll
    for (int K2 = 0; K2 < 8; ++K2)
      cb[k3r * 72 + K2 * 9 + g1] = r[K2];     // L2[k3][K2][g1], pad 9
    __syncthreads();

    // ---- step 3: 8-pt FFT over g1 -> X[k3f + 8*K2f + 64*K1] ----
    float2 s[8];
    #pragma unroll
    for (int gg = 0; gg < 8; ++gg)
      s[BR3[gg]] = cb[k3f * 72 + K2f * 9 + gg];
    fft_reg<3>(s);
    #pragma unroll
    for (int K1 = 0; K1 < 8; ++K1)
      mag[K1] += sqrtf(s[K1].x * s[K1].x + s[K1].y * s[K1].y);
    // next channel's pre-L1-write barrier protects these L2 reads
  }

  if (jvalid) {
    #pragma unroll
    for (int K1 = 0; K1 < 8; ++K1) {
      int row = k3f + 8 * K2f + 64 * K1;
      int code = binsNat[row * W2P + j];
      // scale: ortho (1/512) * channel mean (1/3) = 1/1536
      float m = log1pf(mag[K1] * (1.0f / 1536.0f));
      atomicAdd(&hist[code & 15], m);
      atomicAdd(&hist[16 + (code >> 4)], m);
    }
  }
  __syncthreads();
  int b = b0 + b_local;
  if (t < 24) partial[((size_t)b * NTILE + tile) * 24 + t] = hist[t];
}

// Pass 3: one block per batch. Reduce NTILE partials, normalize, project.
__global__ __launch_bounds__(TPB) void pass3_kernel(
    const float* __restrict__ partial, const float* __restrict__ W,
    const float* __restrict__ bias, float* __restrict__ out) {
  __shared__ float h[24];
  __shared__ float hn[24];
  int b = blockIdx.x;
  int t = threadIdx.x;
  if (t < 24) {
    float s = 0.0f;
    for (int tile = 0; tile < NTILE; tile++)
      s += partial[((size_t)b * NTILE + tile) * 24 + t];
    h[t] = s;
  }
  __syncthreads();
  if (t == 0) {
    float rs = 0.0f, as = 0.0f;
    for (int k = 0; k < 16; k++) rs += h[k];
    for (int k = 16; k < 24; k++) as += h[k];
    for (int k = 0; k < 16; k++) hn[k] = h[k] / (rs + 1e-6f);
    for (int k = 16; k < 24; k++) hn[k] = h[k] / (as + 1e-6f);
  }
  __syncthreads();
  if (t < 64) {
    float acc = bias[t];
    #pragma unroll
    for (int k = 0; k < 24; k++) acc += hn[k] * W[t * 24 + k];
    out[b * 64 + t] = acc;
  }
}

extern "C" void kernel_launch(void* const* d_in, const int* in_sizes, int n_in,
                              void* d_out, int out_size, void* d_ws, size_t ws_size,
                              hipStream_t stream) {
  const float* x    = (const float*)d_in[0];   // [64,3,512,512]
  const float* W    = (const float*)d_in[1];   // [64,24]
  const float* bias = (const float*)d_in[2];   // [64]
  float* out = (float*)d_out;                  // [64,64]

  // ws layout: partial hists | bin table | complex intermediate F
  const size_t partial_bytes = (size_t)64 * NTILE * 24 * sizeof(float);
  size_t off_bins = (partial_bytes + 255) & ~(size_t)255;
  const size_t bins_bytes = (size_t)512 * W2P;
  size_t off_F = ((off_bins + bins_bytes) + 255) & ~(size_t)255;

  float* partial = (float*)d_ws;
  unsigned char* binsNat = (unsigned char*)d_ws + off_bins;
  float2* F = (float2*)((char*)d_ws + off_F);

  const size_t per_batch = (size_t)3 * 512 * W2P * sizeof(float2);  // 3.34 MB
  size_t avail = ws_size > off_F ? ws_size - off_F : 0;
  int bpc = (int)(avail / per_batch);
  if (bpc < 1) bpc = 1;
  if (bpc > 64) bpc = 64;

  pass0_kernel<<<512, TPB, 0, stream>>>(binsNat);

  for (int b0 = 0; b0 < 64; b0 += bpc) {
    int nb = (64 - b0) < bpc ? (64 - b0) : bpc;
    pass1_kernel<<<nb * 3 * 256, TPB, 0, stream>>>(x, F, b0 * 3);
    pass2_kernel<<<nb * NTILE, TPB, 0, stream>>>(F, binsNat, partial, b0);
  }
  pass3_kernel<<<64, TPB, 0, stream>>>(partial, W, bias, out);
}

// Round 6
// 338.159 us; speedup vs baseline: 1.0735x; 1.0735x over previous
//
#include <hip/hip_runtime.h>
#include <math.h>

// SpectrumHead: rfft2(512x512) magnitude -> radial/angular histogram -> linear proj.
// B=64, C=3, H=512, W=512, W2=257 (padded to 272), K_BINS=16, O_BINS=8, proj=64.
//
// Pass 0: bin-code table binsNat[row][j] = rb | ob<<4 (natural row order).
// Pass 1: row real-FFTs, 2 rows packed per complex 512-pt DIT FFT (LDS twiddles,
//         XOR-swizzled LDS), write [512][272] complex intermediate.
// Pass 2: column FFTs via three-step 512 = 8x8x8 register FFT. TPB=512:
//         8 columns/block (64B global segments), 64 threads/column, 8 pts/thread.
//         Two LDS transposes share one 34 KB buffer; layouts are analytically
//         conflict-free (stride 530 = 2 mod 16; [k3][u] unit-stride; XOR on L2).
//         launch_bounds(512,6): cap 85 VGPR (need ~60) -> no spill, 3 blocks/CU.
// Pass 3: reduce tile-partials per batch, normalize, h @ W.T + b.

#define TPB 256
#define TPB2 512
#define PI_F 3.14159265358979323846f
#define TWO_PI_F 6.28318530717958647692f
#define W2 257
#define W2P 272            // padded row stride in float2
#define NTILE 33           // ceil(257/8): 8 columns per pass2 block
#define CS 530             // per-column float2 stride (>=512, ==2 mod 16)
#define SW(p) ((p) ^ (((p) >> 5) & 15))   // pass1 LDS anti-conflict swizzle

__device__ __forceinline__ int brev9(int p) { return (int)(__brev((unsigned)p) >> 23); }

// exp(-2*pi*i*k/32), k = 0..15
static constexpr float TW32_RE[16] = {
   1.0f,          0.98078528f,  0.92387953f,  0.83146961f,
   0.70710678f,   0.55557023f,  0.38268343f,  0.19509032f,
   0.0f,         -0.19509032f, -0.38268343f, -0.55557023f,
  -0.70710678f,  -0.83146961f, -0.92387953f, -0.98078528f };
static constexpr float TW32_IM[16] = {
  -0.0f,         -0.19509032f, -0.38268343f, -0.55557023f,
  -0.70710678f,  -0.83146961f, -0.92387953f, -0.98078528f,
  -1.0f,         -0.98078528f, -0.92387953f, -0.83146961f,
  -0.70710678f,  -0.55557023f, -0.38268343f, -0.19509032f };

static constexpr int BR3[8] = {0,4,2,6,1,5,3,7};

// In-register DIT FFT, N = 2^LOGN, twiddles from TW32 (k = jj<<(4-s)).
// Input bit-rev permuted; output natural order. Fully unrolled -> VGPRs.
template <int LOGN>
__device__ __forceinline__ void fft_reg(float2* z) {
  const int N = 1 << LOGN;
  #pragma unroll
  for (int s = 0; s < LOGN; ++s) {
    const int h = 1 << s;
    #pragma unroll
    for (int g0 = 0; g0 < N; g0 += 2 * h) {
      #pragma unroll
      for (int jj = 0; jj < h; ++jj) {
        const int k = jj << (4 - s);
        const float wr = TW32_RE[k], wi = TW32_IM[k];
        float2 a = z[g0 + jj];
        float2 b = z[g0 + jj + h];
        float tr = b.x * wr - b.y * wi;
        float ti = b.x * wi + b.y * wr;
        z[g0 + jj]     = make_float2(a.x + tr, a.y + ti);
        z[g0 + jj + h] = make_float2(a.x - tr, a.y - ti);
      }
    }
  }
}

__device__ __forceinline__ void get_bins(int i, int j, int& rb, int& ob) {
  float yy = -1.0f + (float)i * (2.0f / 511.0f);
  float xx = (float)j * (1.0f / 256.0f);
  float rr = sqrtf(yy * yy + xx * xx);
  rr = fminf(rr, 1.0f - 1e-8f);
  float th = atan2f(yy, xx + 1e-9f) + 1.57079632679489662f;
  rb = (int)(rr * 16.0f);
  rb = rb < 0 ? 0 : (rb > 15 ? 15 : rb);
  ob = (int)((th / PI_F) * 8.0f);
  ob = ob < 0 ? 0 : (ob > 7 ? 7 : ob);
}

// Pass 0: bin table, natural row order. blockIdx.x = row i.
__global__ __launch_bounds__(TPB) void pass0_kernel(unsigned char* __restrict__ binsNat) {
  int i = blockIdx.x;
  #pragma unroll
  for (int e = 0; e < 2; e++) {
    int j = threadIdx.x + e * 256;
    if (j < W2) {
      int rb, ob;
      get_bins(i, j, rb, ob);
      binsNat[i * W2P + j] = (unsigned char)(rb | (ob << 4));
    }
  }
}

// Pass 1: blockIdx.x = ic_local*256 + rpair. Two real rows -> one complex DIT FFT.
__global__ __launch_bounds__(TPB) void pass1_kernel(
    const float* __restrict__ x, float2* __restrict__ F, int ic0) {
  __shared__ float2 buf[512];
  __shared__ float2 tw[256];
  int t = threadIdx.x;
  int bid = blockIdx.x;
  int rpair = bid & 255;
  int ic_local = bid >> 8;
  const float* row0 = x + (((size_t)(ic0 + ic_local)) * 512 + (size_t)rpair * 2) * 512;
  const float* row1 = row0 + 512;

  {
    float sn, cs;
    sincosf(-TWO_PI_F * (float)t * (1.0f / 512.0f), &sn, &cs);
    tw[t] = make_float2(cs, sn);
  }

  #pragma unroll
  for (int e = 0; e < 2; e++) {
    int i = t + e * 256;
    int dst = brev9(i);
    buf[SW(dst)] = make_float2(row0[i], row1[i]);
  }
  __syncthreads();

  #pragma unroll
  for (int s = 0; s < 9; s++) {
    int h = 1 << s;
    int jj = t & (h - 1);
    int idx = ((t >> s) << (s + 1)) + jj;
    float2 w = tw[jj << (8 - s)];
    float2 a = buf[SW(idx)];
    float2 b = buf[SW(idx + h)];
    float2 wb = make_float2(b.x * w.x - b.y * w.y, b.x * w.y + b.y * w.x);
    buf[SW(idx)]     = make_float2(a.x + wb.x, a.y + wb.y);
    buf[SW(idx + h)] = make_float2(a.x - wb.x, a.y - wb.y);
    __syncthreads();
  }

  float2* out0 = F + ((size_t)ic_local * 512 + (size_t)rpair * 2) * W2P;
  float2* out1 = out0 + W2P;
  int k = t;
  int km = (512 - k) & 511;
  float2 zk = buf[SW(k)];
  float2 zm = buf[SW(km)];
  out0[k] = make_float2(0.5f * (zk.x + zm.x), 0.5f * (zk.y - zm.y));
  out1[k] = make_float2(0.5f * (zk.y + zm.y), -0.5f * (zk.x - zm.x));
  if (t == 0) {
    float2 z = buf[SW(256)];
    out0[256] = make_float2(z.x, 0.0f);
    out1[256] = make_float2(z.y, 0.0f);
  }
}

// Pass 2: blockIdx.x = b_local*NTILE + tile. 8 columns/block, 8x8x8 reg FFT.
// Thread t: col = t&7, u = t>>3 (0..63); per wave: ulocal = u&7, w = u>>3.
//   step1 (role u): z[m] = f[u+64m]; FFT8 -> A_u[k3]; twiddle W_512^(u k3);
//     store L1[k3][u] at col*CS + k3*64 + u.
//   step2 (role g1=ulocal, k3r=w): r[g2] = L1[k3r][g1+8g2]; FFT8 -> D[K2];
//     twiddle W_64^(g1 K2); store L2 at col*CS + k3r*64 + K2*8 + (g1^K2).
//   step3 (role k3f=w, K2f=ulocal): s[gg] = L2[k3f][K2f][gg] (addr +(gg^K2f));
//     FFT8 -> X[k3f + 8 K2f + 64 K1]; magnitude accumulate over channels.
// All four LDS phases: exactly 4 lanes per bank-pair (b64 floor) -> conflict-free.
__global__ __launch_bounds__(TPB2, 6) void pass2_kernel(
    const float2* __restrict__ F, const unsigned char* __restrict__ binsNat,
    float* __restrict__ partial, int b0) {
  __shared__ float2 xbuf[8 * CS];        // 33.9 KB, L1/L2 time-share
  __shared__ float2 tw512[512];          // exp(-2pi i k/512)
  __shared__ float hist[24];
  int t = threadIdx.x;
  int tile = blockIdx.x % NTILE;
  int b_local = blockIdx.x / NTILE;
  int col = t & 7;
  int u = t >> 3;                  // 0..63
  int j = tile * 8 + col;
  bool jvalid = (j < W2);
  float2* cb = xbuf + col * CS;

  {
    float sn, cs;
    sincosf(-TWO_PI_F * (float)t * (1.0f / 512.0f), &sn, &cs);
    tw512[t] = make_float2(cs, sn);
  }
  if (t < 24) hist[t] = 0.0f;

  const int ul = u & 7;            // g1 (step2) / K2f (step3)
  const int w  = u >> 3;           // k3r (step2) / k3f (step3)

  const float2* Fb = F + (size_t)(b_local * 3) * (512 * W2P);

  float mag[8];
  #pragma unroll
  for (int q = 0; q < 8; ++q) mag[q] = 0.0f;

  for (int c = 0; c < 3; ++c) {
    // ---- step 1: FFT8 over m (rows u + 64m), twiddle W_512^(u*k3) ----
    const float2* colp = Fb + (size_t)c * (512 * W2P) + (size_t)u * W2P + j;
    float2 z[8];
    #pragma unroll
    for (int m = 0; m < 8; ++m) {
      float2 v = make_float2(0.0f, 0.0f);
      if (jvalid) v = colp[(size_t)m * (64 * W2P)];
      z[BR3[m]] = v;
    }
    fft_reg<3>(z);                       // z[k3] = A_u[k3]
    #pragma unroll
    for (int k3 = 0; k3 < 8; ++k3) {
      float2 ww = tw512[u * k3];
      float2 v = z[k3];
      z[k3] = make_float2(v.x * ww.x - v.y * ww.y, v.x * ww.y + v.y * ww.x);
    }
    __syncthreads();                     // prev channel's step-3 reads complete
    #pragma unroll
    for (int k3 = 0; k3 < 8; ++k3)
      cb[k3 * 64 + u] = z[k3];           // L1[k3][u]
    __syncthreads();

    // ---- step 2: FFT8 over g2, twiddle W_64^(g1*K2) ----
    float2 r[8];
    #pragma unroll
    for (int g2 = 0; g2 < 8; ++g2)
      r[BR3[g2]] = cb[w * 64 + ul + 8 * g2];   // L1[k3r=w][g1+8g2]
    fft_reg<3>(r);                       // r[K2] = D[g1][k3r][K2]
    #pragma unroll
    for (int K2 = 0; K2 < 8; ++K2) {
      float2 ww = tw512[(ul * K2) << 3]; // W_64^(g1 K2) = W_512^(8 g1 K2)
      float2 v = r[K2];
      r[K2] = make_float2(v.x * ww.x - v.y * ww.y, v.x * ww.y + v.y * ww.x);
    }
    __syncthreads();                     // all L1 reads done before overwrite
    #pragma unroll
    for (int K2 = 0; K2 < 8; ++K2)
      cb[w * 64 + K2 * 8 + (ul ^ K2)] = r[K2];   // L2[k3][K2][g1], XOR swizzle
    __syncthreads();

    // ---- step 3: FFT8 over g1 -> X[k3f + 8*K2f + 64*K1] ----
    float2 s[8];
    #pragma unroll
    for (int gg = 0; gg < 8; ++gg)
      s[BR3[gg]] = cb[w * 64 + ul * 8 + (gg ^ ul)];  // L2[k3f=w][K2f=ul][gg]
    fft_reg<3>(s);
    #pragma unroll
    for (int K1 = 0; K1 < 8; ++K1)
      mag[K1] += sqrtf(s[K1].x * s[K1].x + s[K1].y * s[K1].y);
    // next channel's pre-L1-write barrier protects these L2 reads
  }

  if (jvalid) {
    #pragma unroll
    for (int K1 = 0; K1 < 8; ++K1) {
      int row = w + 8 * ul + 64 * K1;    // k3f + 8*K2f + 64*K1
      int code = binsNat[row * W2P + j];
      // scale: ortho (1/512) * channel mean (1/3) = 1/1536
      float m = log1pf(mag[K1] * (1.0f / 1536.0f));
      atomicAdd(&hist[code & 15], m);
      atomicAdd(&hist[16 + (code >> 4)], m);
    }
  }
  __syncthreads();
  int b = b0 + b_local;
  if (t < 24) partial[((size_t)b * NTILE + tile) * 24 + t] = hist[t];
}

// Pass 3: one block per batch. Reduce NTILE partials, normalize, project.
__global__ __launch_bounds__(TPB) void pass3_kernel(
    const float* __restrict__ partial, const float* __restrict__ W,
    const float* __restrict__ bias, float* __restrict__ out) {
  __shared__ float h[24];
  __shared__ float hn[24];
  int b = blockIdx.x;
  int t = threadIdx.x;
  if (t < 24) {
    float s = 0.0f;
    for (int tile = 0; tile < NTILE; tile++)
      s += partial[((size_t)b * NTILE + tile) * 24 + t];
    h[t] = s;
  }
  __syncthreads();
  if (t == 0) {
    float rs = 0.0f, as = 0.0f;
    for (int k = 0; k < 16; k++) rs += h[k];
    for (int k = 16; k < 24; k++) as += h[k];
    for (int k = 0; k < 16; k++) hn[k] = h[k] / (rs + 1e-6f);
    for (int k = 16; k < 24; k++) hn[k] = h[k] / (as + 1e-6f);
  }
  __syncthreads();
  if (t < 64) {
    float acc = bias[t];
    #pragma unroll
    for (int k = 0; k < 24; k++) acc += hn[k] * W[t * 24 + k];
    out[b * 64 + t] = acc;
  }
}

extern "C" void kernel_launch(void* const* d_in, const int* in_sizes, int n_in,
                              void* d_out, int out_size, void* d_ws, size_t ws_size,
                              hipStream_t stream) {
  const float* x    = (const float*)d_in[0];   // [64,3,512,512]
  const float* W    = (const float*)d_in[1];   // [64,24]
  const float* bias = (const float*)d_in[2];   // [64]
  float* out = (float*)d_out;                  // [64,64]

  // ws layout: partial hists | bin table | complex intermediate F
  const size_t partial_bytes = (size_t)64 * NTILE * 24 * sizeof(float);
  size_t off_bins = (partial_bytes + 255) & ~(size_t)255;
  const size_t bins_bytes = (size_t)512 * W2P;
  size_t off_F = ((off_bins + bins_bytes) + 255) & ~(size_t)255;

  float* partial = (float*)d_ws;
  unsigned char* binsNat = (unsigned char*)d_ws + off_bins;
  float2* F = (float2*)((char*)d_ws + off_F);

  const size_t per_batch = (size_t)3 * 512 * W2P * sizeof(float2);  // 3.34 MB
  size_t avail = ws_size > off_F ? ws_size - off_F : 0;
  int bpc = (int)(avail / per_batch);
  if (bpc < 1) bpc = 1;
  if (bpc > 64) bpc = 64;

  pass0_kernel<<<512, TPB, 0, stream>>>(binsNat);

  for (int b0 = 0; b0 < 64; b0 += bpc) {
    int nb = (64 - b0) < bpc ? (64 - b0) : bpc;
    pass1_kernel<<<nb * 3 * 256, TPB, 0, stream>>>(x, F, b0 * 3);
    pass2_kernel<<<nb * NTILE, TPB2, 0, stream>>>(F, binsNat, partial, b0);
  }
  pass3_kernel<<<64, TPB, 0, stream>>>(partial, W, bias, out);
}

// Round 7
// 302.082 us; speedup vs baseline: 1.2017x; 1.1194x over previous
//
#include <hip/hip_runtime.h>
#include <math.h>

// SpectrumHead: rfft2(512x512) magnitude -> radial/angular histogram -> linear proj.
// B=64, C=3, H=512, W=512, W2=257 (padded to 272), K_BINS=16, O_BINS=8, proj=64.
//
// Pass 0: bin-code table binsNat[row][j] = rb | ob<<4 (natural row order).
// Pass 1: row real-FFTs, 2 rows packed per complex 512-pt DIT FFT (LDS twiddles,
//         XOR-swizzled LDS), write [512][272] complex intermediate.
// Pass 2: column FFTs, three-step 512 = 8x8x8 register FFT. TPB=1024:
//         16 columns/block (full 128B lines, L3-friendly), 64 threads/column,
//         8 pts/thread. Per-column LDS stride 529 (== 1 mod 16) makes every
//         LDS phase conflict-free (16-lane groups: fixed offset x 16 distinct
//         cols -> all 16 bank-pairs). 68 KB LDS -> 2 blocks/CU, 32 waves/CU.
//         128-bin combined histogram (1 atomic/element), folded to 24 at end.
// Pass 3: reduce tile-partials per batch, normalize, h @ W.T + b.

#define TPB 256
#define TPB2 1024
#define PI_F 3.14159265358979323846f
#define TWO_PI_F 6.28318530717958647692f
#define W2 257
#define W2P 272            // padded row stride in float2
#define NTILE 17           // ceil(257/16): 16 columns per pass2 block
#define CS 529             // per-column float2 stride (>=512, == 1 mod 16)
#define SW(p) ((p) ^ (((p) >> 5) & 15))   // pass1 LDS anti-conflict swizzle

__device__ __forceinline__ int brev9(int p) { return (int)(__brev((unsigned)p) >> 23); }

// exp(-2*pi*i*k/32), k = 0..15
static constexpr float TW32_RE[16] = {
   1.0f,          0.98078528f,  0.92387953f,  0.83146961f,
   0.70710678f,   0.55557023f,  0.38268343f,  0.19509032f,
   0.0f,         -0.19509032f, -0.38268343f, -0.55557023f,
  -0.70710678f,  -0.83146961f, -0.92387953f, -0.98078528f };
static constexpr float TW32_IM[16] = {
  -0.0f,         -0.19509032f, -0.38268343f, -0.55557023f,
  -0.70710678f,  -0.83146961f, -0.92387953f, -0.98078528f,
  -1.0f,         -0.98078528f, -0.92387953f, -0.83146961f,
  -0.70710678f,  -0.55557023f, -0.38268343f, -0.19509032f };

static constexpr int BR3[8] = {0,4,2,6,1,5,3,7};

// In-register DIT FFT, N = 2^LOGN, twiddles from TW32 (k = jj<<(4-s)).
// Input bit-rev permuted; output natural order. Fully unrolled -> VGPRs.
template <int LOGN>
__device__ __forceinline__ void fft_reg(float2* z) {
  const int N = 1 << LOGN;
  #pragma unroll
  for (int s = 0; s < LOGN; ++s) {
    const int h = 1 << s;
    #pragma unroll
    for (int g0 = 0; g0 < N; g0 += 2 * h) {
      #pragma unroll
      for (int jj = 0; jj < h; ++jj) {
        const int k = jj << (4 - s);
        const float wr = TW32_RE[k], wi = TW32_IM[k];
        float2 a = z[g0 + jj];
        float2 b = z[g0 + jj + h];
        float tr = b.x * wr - b.y * wi;
        float ti = b.x * wi + b.y * wr;
        z[g0 + jj]     = make_float2(a.x + tr, a.y + ti);
        z[g0 + jj + h] = make_float2(a.x - tr, a.y - ti);
      }
    }
  }
}

__device__ __forceinline__ void get_bins(int i, int j, int& rb, int& ob) {
  float yy = -1.0f + (float)i * (2.0f / 511.0f);
  float xx = (float)j * (1.0f / 256.0f);
  float rr = sqrtf(yy * yy + xx * xx);
  rr = fminf(rr, 1.0f - 1e-8f);
  float th = atan2f(yy, xx + 1e-9f) + 1.57079632679489662f;
  rb = (int)(rr * 16.0f);
  rb = rb < 0 ? 0 : (rb > 15 ? 15 : rb);
  ob = (int)((th / PI_F) * 8.0f);
  ob = ob < 0 ? 0 : (ob > 7 ? 7 : ob);
}

// Pass 0: bin table, natural row order. blockIdx.x = row i.
__global__ __launch_bounds__(TPB) void pass0_kernel(unsigned char* __restrict__ binsNat) {
  int i = blockIdx.x;
  #pragma unroll
  for (int e = 0; e < 2; e++) {
    int j = threadIdx.x + e * 256;
    if (j < W2) {
      int rb, ob;
      get_bins(i, j, rb, ob);
      binsNat[i * W2P + j] = (unsigned char)(rb | (ob << 4));
    }
  }
}

// Pass 1: blockIdx.x = ic_local*256 + rpair. Two real rows -> one complex DIT FFT.
__global__ __launch_bounds__(TPB) void pass1_kernel(
    const float* __restrict__ x, float2* __restrict__ F, int ic0) {
  __shared__ float2 buf[512];
  __shared__ float2 tw[256];
  int t = threadIdx.x;
  int bid = blockIdx.x;
  int rpair = bid & 255;
  int ic_local = bid >> 8;
  const float* row0 = x + (((size_t)(ic0 + ic_local)) * 512 + (size_t)rpair * 2) * 512;
  const float* row1 = row0 + 512;

  {
    float sn, cs;
    sincosf(-TWO_PI_F * (float)t * (1.0f / 512.0f), &sn, &cs);
    tw[t] = make_float2(cs, sn);
  }

  #pragma unroll
  for (int e = 0; e < 2; e++) {
    int i = t + e * 256;
    int dst = brev9(i);
    buf[SW(dst)] = make_float2(row0[i], row1[i]);
  }
  __syncthreads();

  #pragma unroll
  for (int s = 0; s < 9; s++) {
    int h = 1 << s;
    int jj = t & (h - 1);
    int idx = ((t >> s) << (s + 1)) + jj;
    float2 w = tw[jj << (8 - s)];
    float2 a = buf[SW(idx)];
    float2 b = buf[SW(idx + h)];
    float2 wb = make_float2(b.x * w.x - b.y * w.y, b.x * w.y + b.y * w.x);
    buf[SW(idx)]     = make_float2(a.x + wb.x, a.y + wb.y);
    buf[SW(idx + h)] = make_float2(a.x - wb.x, a.y - wb.y);
    __syncthreads();
  }

  float2* out0 = F + ((size_t)ic_local * 512 + (size_t)rpair * 2) * W2P;
  float2* out1 = out0 + W2P;
  int k = t;
  int km = (512 - k) & 511;
  float2 zk = buf[SW(k)];
  float2 zm = buf[SW(km)];
  out0[k] = make_float2(0.5f * (zk.x + zm.x), 0.5f * (zk.y - zm.y));
  out1[k] = make_float2(0.5f * (zk.y + zm.y), -0.5f * (zk.x - zm.x));
  if (t == 0) {
    float2 z = buf[SW(256)];
    out0[256] = make_float2(z.x, 0.0f);
    out1[256] = make_float2(z.y, 0.0f);
  }
}

// Pass 2: blockIdx.x = b_local*NTILE + tile. 16 columns/block, 8x8x8 reg FFT.
// Thread t: col = t&15, u = t>>4 (0..63); ul = u&7, w = u>>3.
//   step1 (role u): z[m] = f[u+64m]; FFT8 -> A_u[k3]; twiddle W_512^(u k3);
//     store L1[k3][u] at col*CS + k3*64 + u.
//   step2 (role g1=ul, k3r=w): r[g2] = L1[k3r][g1+8g2]; FFT8 -> D[K2];
//     twiddle W_64^(g1 K2); store L2[k3r][K2][g1] at col*CS + k3r*64 + K2*8 + g1.
//   step3 (role k3f=w, K2f=ul): s[gg] = L2[k3f][K2f][gg]; FFT8 ->
//     X[k3f + 8 K2f + 64 K1]; magnitude accumulate over channels.
// CS == 1 mod 16: every 16-lane group has fixed intra-col offset and 16 distinct
// cols -> all 16 bank-pairs hit once -> conflict-free (b64 floor) in all phases.
__global__ __launch_bounds__(TPB2, 8) void pass2_kernel(
    const float2* __restrict__ F, const unsigned char* __restrict__ binsNat,
    float* __restrict__ partial, int b0) {
  __shared__ float2 xbuf[16 * CS];       // 67.7 KB, L1/L2 time-share
  __shared__ float2 tw512[512];          // exp(-2pi i k/512)
  __shared__ float hist[128];            // combined bins: rb + 16*ob
  int t = threadIdx.x;
  int tile = blockIdx.x % NTILE;
  int b_local = blockIdx.x / NTILE;
  int col = t & 15;
  int u = t >> 4;                  // 0..63
  int j = tile * 16 + col;
  bool jvalid = (j < W2);
  float2* cb = xbuf + col * CS;

  if (t < 512) {
    float sn, cs;
    sincosf(-TWO_PI_F * (float)t * (1.0f / 512.0f), &sn, &cs);
    tw512[t] = make_float2(cs, sn);
  }
  if (t < 128) hist[t] = 0.0f;

  const int ul = u & 7;            // g1 (step2) / K2f (step3)
  const int w  = u >> 3;           // k3r (step2) / k3f (step3)

  const float2* Fb = F + (size_t)(b_local * 3) * (512 * W2P);

  float mag[8];
  #pragma unroll
  for (int q = 0; q < 8; ++q) mag[q] = 0.0f;

  for (int c = 0; c < 3; ++c) {
    // ---- step 1: FFT8 over m (rows u + 64m), twiddle W_512^(u*k3) ----
    const float2* colp = Fb + (size_t)c * (512 * W2P) + (size_t)u * W2P + j;
    float2 z[8];
    #pragma unroll
    for (int m = 0; m < 8; ++m) {
      float2 v = make_float2(0.0f, 0.0f);
      if (jvalid) v = colp[(size_t)m * (64 * W2P)];
      z[BR3[m]] = v;
    }
    fft_reg<3>(z);                       // z[k3] = A_u[k3]
    #pragma unroll
    for (int k3 = 0; k3 < 8; ++k3) {
      float2 ww = tw512[u * k3];
      float2 v = z[k3];
      z[k3] = make_float2(v.x * ww.x - v.y * ww.y, v.x * ww.y + v.y * ww.x);
    }
    __syncthreads();        // prev channel's step-3 reads (and tw/hist init) done
    #pragma unroll
    for (int k3 = 0; k3 < 8; ++k3)
      cb[k3 * 64 + u] = z[k3];           // L1[k3][u]
    __syncthreads();

    // ---- step 2: FFT8 over g2, twiddle W_64^(g1*K2) ----
    float2 r[8];
    #pragma unroll
    for (int g2 = 0; g2 < 8; ++g2)
      r[BR3[g2]] = cb[w * 64 + ul + 8 * g2];   // L1[k3r=w][g1+8g2]
    fft_reg<3>(r);                       // r[K2] = D[g1][k3r][K2]
    #pragma unroll
    for (int K2 = 0; K2 < 8; ++K2) {
      float2 ww = tw512[(ul * K2) << 3]; // W_64^(g1 K2) = W_512^(8 g1 K2)
      float2 v = r[K2];
      r[K2] = make_float2(v.x * ww.x - v.y * ww.y, v.x * ww.y + v.y * ww.x);
    }
    __syncthreads();                     // all L1 reads done before overwrite
    #pragma unroll
    for (int K2 = 0; K2 < 8; ++K2)
      cb[w * 64 + K2 * 8 + ul] = r[K2];  // L2[k3][K2][g1]
    __syncthreads();

    // ---- step 3: FFT8 over g1 -> X[k3f + 8*K2f + 64*K1] ----
    float2 s[8];
    #pragma unroll
    for (int gg = 0; gg < 8; ++gg)
      s[BR3[gg]] = cb[w * 64 + ul * 8 + gg];   // L2[k3f=w][K2f=ul][gg]
    fft_reg<3>(s);
    #pragma unroll
    for (int K1 = 0; K1 < 8; ++K1)
      mag[K1] += sqrtf(s[K1].x * s[K1].x + s[K1].y * s[K1].y);
    // next channel's pre-L1-write barrier protects these L2 reads
  }

  if (jvalid) {
    #pragma unroll
    for (int K1 = 0; K1 < 8; ++K1) {
      int row = w + 8 * ul + 64 * K1;    // k3f + 8*K2f + 64*K1
      int code = binsNat[row * W2P + j]; // rb | ob<<4
      // scale: ortho (1/512) * channel mean (1/3) = 1/1536
      float m = log1pf(mag[K1] * (1.0f / 1536.0f));
      atomicAdd(&hist[code], m);         // single combined-bin atomic
    }
  }
  __syncthreads();

  // fold 128 combined bins -> 16 radial + 8 angular partials
  int b = b0 + b_local;
  if (t < 16) {
    float s = 0.0f;
    #pragma unroll
    for (int ob = 0; ob < 8; ++ob) s += hist[t + 16 * ob];
    partial[((size_t)b * NTILE + tile) * 24 + t] = s;
  } else if (t < 24) {
    float s = 0.0f;
    int ob = t - 16;
    #pragma unroll
    for (int rb = 0; rb < 16; ++rb) s += hist[rb + 16 * ob];
    partial[((size_t)b * NTILE + tile) * 24 + t] = s;
  }
}

// Pass 3: one block per batch. Reduce NTILE partials, normalize, project.
__global__ __launch_bounds__(TPB) void pass3_kernel(
    const float* __restrict__ partial, const float* __restrict__ W,
    const float* __restrict__ bias, float* __restrict__ out) {
  __shared__ float h[24];
  __shared__ float hn[24];
  int b = blockIdx.x;
  int t = threadIdx.x;
  if (t < 24) {
    float s = 0.0f;
    for (int tile = 0; tile < NTILE; tile++)
      s += partial[((size_t)b * NTILE + tile) * 24 + t];
    h[t] = s;
  }
  __syncthreads();
  if (t == 0) {
    float rs = 0.0f, as = 0.0f;
    for (int k = 0; k < 16; k++) rs += h[k];
    for (int k = 16; k < 24; k++) as += h[k];
    for (int k = 0; k < 16; k++) hn[k] = h[k] / (rs + 1e-6f);
    for (int k = 16; k < 24; k++) hn[k] = h[k] / (as + 1e-6f);
  }
  __syncthreads();
  if (t < 64) {
    float acc = bias[t];
    #pragma unroll
    for (int k = 0; k < 24; k++) acc += hn[k] * W[t * 24 + k];
    out[b * 64 + t] = acc;
  }
}

extern "C" void kernel_launch(void* const* d_in, const int* in_sizes, int n_in,
                              void* d_out, int out_size, void* d_ws, size_t ws_size,
                              hipStream_t stream) {
  const float* x    = (const float*)d_in[0];   // [64,3,512,512]
  const float* W    = (const float*)d_in[1];   // [64,24]
  const float* bias = (const float*)d_in[2];   // [64]
  float* out = (float*)d_out;                  // [64,64]

  // ws layout: partial hists | bin table | complex intermediate F
  const size_t partial_bytes = (size_t)64 * NTILE * 24 * sizeof(float);
  size_t off_bins = (partial_bytes + 255) & ~(size_t)255;
  const size_t bins_bytes = (size_t)512 * W2P;
  size_t off_F = ((off_bins + bins_bytes) + 255) & ~(size_t)255;

  float* partial = (float*)d_ws;
  unsigned char* binsNat = (unsigned char*)d_ws + off_bins;
  float2* F = (float2*)((char*)d_ws + off_F);

  const size_t per_batch = (size_t)3 * 512 * W2P * sizeof(float2);  // 3.34 MB
  size_t avail = ws_size > off_F ? ws_size - off_F : 0;
  int bpc = (int)(avail / per_batch);
  if (bpc < 1) bpc = 1;
  if (bpc > 64) bpc = 64;

  pass0_kernel<<<512, TPB, 0, stream>>>(binsNat);

  for (int b0 = 0; b0 < 64; b0 += bpc) {
    int nb = (64 - b0) < bpc ? (64 - b0) : bpc;
    pass1_kernel<<<nb * 3 * 256, TPB, 0, stream>>>(x, F, b0 * 3);
    pass2_kernel<<<nb * NTILE, TPB2, 0, stream>>>(F, binsNat, partial, b0);
  }
  pass3_kernel<<<64, TPB, 0, stream>>>(partial, W, bias, out);
}

// Round 8
// 261.110 us; speedup vs baseline: 1.3902x; 1.1569x over previous
//
#include <hip/hip_runtime.h>
#include <math.h>

// SpectrumHead: rfft2(512x512) magnitude -> radial/angular histogram -> linear proj.
// B=64, C=3, H=512, W=512, W2=257 (padded to 272), K_BINS=16, O_BINS=8, proj=64.
//
// Pass 0: bin-code table binsNat[row][j] = rb | ob<<4 (natural row order).
// Pass 1: row real-FFTs, 2 rows packed per complex 512-pt DIT FFT (LDS twiddles,
//         XOR-swizzled LDS), write [512][272] complex intermediate.
// Pass 2: column FFTs, three-step 512 = 8x8x8 register FFT. TPB=1024:
//         16 columns/block (full 128B lines), 64 threads/column, 8 pts/thread.
//         Per-column LDS stride 529 (== 1 mod 16): every LDS phase conflict-free.
//         LAUNCH BOUNDS CALIBRATION (empirical, this toolchain): reported VGPR
//         cap ~= 256/arg2 (r3:3->80, r4/6:6->40, r7:8->32). Kernel needs ~45,
//         so arg2=4 (cap 64) -> no spill; occupancy LDS-limited at 2 blocks/CU.
//         128-bin combined histogram (1 atomic/element), folded to 24 at end.
// Pass 3: reduce tile-partials per batch, normalize, h @ W.T + b.

#define TPB 256
#define TPB2 1024
#define PI_F 3.14159265358979323846f
#define TWO_PI_F 6.28318530717958647692f
#define W2 257
#define W2P 272            // padded row stride in float2
#define NTILE 17           // ceil(257/16): 16 columns per pass2 block
#define CS 529             // per-column float2 stride (>=512, == 1 mod 16)
#define SW(p) ((p) ^ (((p) >> 5) & 15))   // pass1 LDS anti-conflict swizzle

__device__ __forceinline__ int brev9(int p) { return (int)(__brev((unsigned)p) >> 23); }

// exp(-2*pi*i*k/32), k = 0..15
static constexpr float TW32_RE[16] = {
   1.0f,          0.98078528f,  0.92387953f,  0.83146961f,
   0.70710678f,   0.55557023f,  0.38268343f,  0.19509032f,
   0.0f,         -0.19509032f, -0.38268343f, -0.55557023f,
  -0.70710678f,  -0.83146961f, -0.92387953f, -0.98078528f };
static constexpr float TW32_IM[16] = {
  -0.0f,         -0.19509032f, -0.38268343f, -0.55557023f,
  -0.70710678f,  -0.83146961f, -0.92387953f, -0.98078528f,
  -1.0f,         -0.98078528f, -0.92387953f, -0.83146961f,
  -0.70710678f,  -0.55557023f, -0.38268343f, -0.19509032f };

static constexpr int BR3[8] = {0,4,2,6,1,5,3,7};

// In-register DIT FFT, N = 2^LOGN, twiddles from TW32 (k = jj<<(4-s)).
// Input bit-rev permuted; output natural order. Fully unrolled -> VGPRs.
template <int LOGN>
__device__ __forceinline__ void fft_reg(float2* z) {
  const int N = 1 << LOGN;
  #pragma unroll
  for (int s = 0; s < LOGN; ++s) {
    const int h = 1 << s;
    #pragma unroll
    for (int g0 = 0; g0 < N; g0 += 2 * h) {
      #pragma unroll
      for (int jj = 0; jj < h; ++jj) {
        const int k = jj << (4 - s);
        const float wr = TW32_RE[k], wi = TW32_IM[k];
        float2 a = z[g0 + jj];
        float2 b = z[g0 + jj + h];
        float tr = b.x * wr - b.y * wi;
        float ti = b.x * wi + b.y * wr;
        z[g0 + jj]     = make_float2(a.x + tr, a.y + ti);
        z[g0 + jj + h] = make_float2(a.x - tr, a.y - ti);
      }
    }
  }
}

__device__ __forceinline__ void get_bins(int i, int j, int& rb, int& ob) {
  float yy = -1.0f + (float)i * (2.0f / 511.0f);
  float xx = (float)j * (1.0f / 256.0f);
  float rr = sqrtf(yy * yy + xx * xx);
  rr = fminf(rr, 1.0f - 1e-8f);
  float th = atan2f(yy, xx + 1e-9f) + 1.57079632679489662f;
  rb = (int)(rr * 16.0f);
  rb = rb < 0 ? 0 : (rb > 15 ? 15 : rb);
  ob = (int)((th / PI_F) * 8.0f);
  ob = ob < 0 ? 0 : (ob > 7 ? 7 : ob);
}

// Pass 0: bin table, natural row order. blockIdx.x = row i.
__global__ __launch_bounds__(TPB) void pass0_kernel(unsigned char* __restrict__ binsNat) {
  int i = blockIdx.x;
  #pragma unroll
  for (int e = 0; e < 2; e++) {
    int j = threadIdx.x + e * 256;
    if (j < W2) {
      int rb, ob;
      get_bins(i, j, rb, ob);
      binsNat[i * W2P + j] = (unsigned char)(rb | (ob << 4));
    }
  }
}

// Pass 1: blockIdx.x = ic_local*256 + rpair. Two real rows -> one complex DIT FFT.
__global__ __launch_bounds__(TPB) void pass1_kernel(
    const float* __restrict__ x, float2* __restrict__ F, int ic0) {
  __shared__ float2 buf[512];
  __shared__ float2 tw[256];
  int t = threadIdx.x;
  int bid = blockIdx.x;
  int rpair = bid & 255;
  int ic_local = bid >> 8;
  const float* row0 = x + (((size_t)(ic0 + ic_local)) * 512 + (size_t)rpair * 2) * 512;
  const float* row1 = row0 + 512;

  {
    float sn, cs;
    sincosf(-TWO_PI_F * (float)t * (1.0f / 512.0f), &sn, &cs);
    tw[t] = make_float2(cs, sn);
  }

  #pragma unroll
  for (int e = 0; e < 2; e++) {
    int i = t + e * 256;
    int dst = brev9(i);
    buf[SW(dst)] = make_float2(row0[i], row1[i]);
  }
  __syncthreads();

  #pragma unroll
  for (int s = 0; s < 9; s++) {
    int h = 1 << s;
    int jj = t & (h - 1);
    int idx = ((t >> s) << (s + 1)) + jj;
    float2 w = tw[jj << (8 - s)];
    float2 a = buf[SW(idx)];
    float2 b = buf[SW(idx + h)];
    float2 wb = make_float2(b.x * w.x - b.y * w.y, b.x * w.y + b.y * w.x);
    buf[SW(idx)]     = make_float2(a.x + wb.x, a.y + wb.y);
    buf[SW(idx + h)] = make_float2(a.x - wb.x, a.y - wb.y);
    __syncthreads();
  }

  float2* out0 = F + ((size_t)ic_local * 512 + (size_t)rpair * 2) * W2P;
  float2* out1 = out0 + W2P;
  int k = t;
  int km = (512 - k) & 511;
  float2 zk = buf[SW(k)];
  float2 zm = buf[SW(km)];
  out0[k] = make_float2(0.5f * (zk.x + zm.x), 0.5f * (zk.y - zm.y));
  out1[k] = make_float2(0.5f * (zk.y + zm.y), -0.5f * (zk.x - zm.x));
  if (t == 0) {
    float2 z = buf[SW(256)];
    out0[256] = make_float2(z.x, 0.0f);
    out1[256] = make_float2(z.y, 0.0f);
  }
}

// Pass 2: blockIdx.x = b_local*NTILE + tile. 16 columns/block, 8x8x8 reg FFT.
// Thread t: col = t&15, u = t>>4 (0..63); ul = u&7, w = u>>3.
//   step1 (role u): z[m] = f[u+64m]; FFT8 -> A_u[k3]; twiddle W_512^(u k3);
//     store L1[k3][u] at col*CS + k3*64 + u.
//   step2 (role g1=ul, k3r=w): r[g2] = L1[k3r][g1+8g2]; FFT8 -> D[K2];
//     twiddle W_64^(g1 K2); store L2[k3r][K2][g1] at col*CS + k3r*64 + K2*8 + g1.
//   step3 (role k3f=w, K2f=ul): s[gg] = L2[k3f][K2f][gg]; FFT8 ->
//     X[k3f + 8 K2f + 64 K1]; magnitude accumulate over channels.
// CS == 1 mod 16: every 16-lane group has fixed intra-col offset and 16 distinct
// cols -> all 16 bank-pairs hit once -> conflict-free (b64 floor) in all phases.
__global__ __launch_bounds__(TPB2, 4) void pass2_kernel(
    const float2* __restrict__ F, const unsigned char* __restrict__ binsNat,
    float* __restrict__ partial, int b0) {
  __shared__ float2 xbuf[16 * CS];       // 67.7 KB, L1/L2 time-share
  __shared__ float2 tw512[512];          // exp(-2pi i k/512)
  __shared__ float hist[128];            // combined bins: rb + 16*ob
  int t = threadIdx.x;
  int tile = blockIdx.x % NTILE;
  int b_local = blockIdx.x / NTILE;
  int col = t & 15;
  int u = t >> 4;                  // 0..63
  int j = tile * 16 + col;
  bool jvalid = (j < W2);
  float2* cb = xbuf + col * CS;

  if (t < 512) {
    float sn, cs;
    sincosf(-TWO_PI_F * (float)t * (1.0f / 512.0f), &sn, &cs);
    tw512[t] = make_float2(cs, sn);
  }
  if (t < 128) hist[t] = 0.0f;
  __syncthreads();                 // tw512/hist visible to all before use

  const int ul = u & 7;            // g1 (step2) / K2f (step3)
  const int w  = u >> 3;           // k3r (step2) / k3f (step3)

  const float2* Fb = F + (size_t)(b_local * 3) * (512 * W2P);

  float mag[8];
  #pragma unroll
  for (int q = 0; q < 8; ++q) mag[q] = 0.0f;

  for (int c = 0; c < 3; ++c) {
    // ---- step 1: FFT8 over m (rows u + 64m), twiddle W_512^(u*k3) ----
    const float2* colp = Fb + (size_t)c * (512 * W2P) + (size_t)u * W2P + j;
    float2 z[8];
    #pragma unroll
    for (int m = 0; m < 8; ++m) {
      float2 v = make_float2(0.0f, 0.0f);
      if (jvalid) v = colp[(size_t)m * (64 * W2P)];
      z[BR3[m]] = v;
    }
    fft_reg<3>(z);                       // z[k3] = A_u[k3]
    #pragma unroll
    for (int k3 = 0; k3 < 8; ++k3) {
      float2 ww = tw512[u * k3];
      float2 v = z[k3];
      z[k3] = make_float2(v.x * ww.x - v.y * ww.y, v.x * ww.y + v.y * ww.x);
    }
    __syncthreads();                     // prev channel's step-3 reads complete
    #pragma unroll
    for (int k3 = 0; k3 < 8; ++k3)
      cb[k3 * 64 + u] = z[k3];           // L1[k3][u]
    __syncthreads();

    // ---- step 2: FFT8 over g2, twiddle W_64^(g1*K2) ----
    float2 r[8];
    #pragma unroll
    for (int g2 = 0; g2 < 8; ++g2)
      r[BR3[g2]] = cb[w * 64 + ul + 8 * g2];   // L1[k3r=w][g1+8g2]
    fft_reg<3>(r);                       // r[K2] = D[g1][k3r][K2]
    #pragma unroll
    for (int K2 = 0; K2 < 8; ++K2) {
      float2 ww = tw512[(ul * K2) << 3]; // W_64^(g1 K2) = W_512^(8 g1 K2)
      float2 v = r[K2];
      r[K2] = make_float2(v.x * ww.x - v.y * ww.y, v.x * ww.y + v.y * ww.x);
    }
    __syncthreads();                     // all L1 reads done before overwrite
    #pragma unroll
    for (int K2 = 0; K2 < 8; ++K2)
      cb[w * 64 + K2 * 8 + ul] = r[K2];  // L2[k3][K2][g1]
    __syncthreads();

    // ---- step 3: FFT8 over g1 -> X[k3f + 8*K2f + 64*K1] ----
    float2 s[8];
    #pragma unroll
    for (int gg = 0; gg < 8; ++gg)
      s[BR3[gg]] = cb[w * 64 + ul * 8 + gg];   // L2[k3f=w][K2f=ul][gg]
    fft_reg<3>(s);
    #pragma unroll
    for (int K1 = 0; K1 < 8; ++K1)
      mag[K1] += sqrtf(s[K1].x * s[K1].x + s[K1].y * s[K1].y);
    // next channel's pre-L1-write barrier protects these L2 reads
  }

  if (jvalid) {
    #pragma unroll
    for (int K1 = 0; K1 < 8; ++K1) {
      int row = w + 8 * ul + 64 * K1;    // k3f + 8*K2f + 64*K1
      int code = binsNat[row * W2P + j]; // rb | ob<<4
      // scale: ortho (1/512) * channel mean (1/3) = 1/1536
      float m = log1pf(mag[K1] * (1.0f / 1536.0f));
      atomicAdd(&hist[code], m);         // single combined-bin atomic
    }
  }
  __syncthreads();

  // fold 128 combined bins -> 16 radial + 8 angular partials
  int b = b0 + b_local;
  if (t < 16) {
    float s = 0.0f;
    #pragma unroll
    for (int ob = 0; ob < 8; ++ob) s += hist[t + 16 * ob];
    partial[((size_t)b * NTILE + tile) * 24 + t] = s;
  } else if (t < 24) {
    float s = 0.0f;
    int ob = t - 16;
    #pragma unroll
    for (int rb = 0; rb < 16; ++rb) s += hist[rb + 16 * ob];
    partial[((size_t)b * NTILE + tile) * 24 + t] = s;
  }
}

// Pass 3: one block per batch. Reduce NTILE partials, normalize, project.
__global__ __launch_bounds__(TPB) void pass3_kernel(
    const float* __restrict__ partial, const float* __restrict__ W,
    const float* __restrict__ bias, float* __restrict__ out) {
  __shared__ float h[24];
  __shared__ float hn[24];
  int b = blockIdx.x;
  int t = threadIdx.x;
  if (t < 24) {
    float s = 0.0f;
    for (int tile = 0; tile < NTILE; tile++)
      s += partial[((size_t)b * NTILE + tile) * 24 + t];
    h[t] = s;
  }
  __syncthreads();
  if (t == 0) {
    float rs = 0.0f, as = 0.0f;
    for (int k = 0; k < 16; k++) rs += h[k];
    for (int k = 16; k < 24; k++) as += h[k];
    for (int k = 0; k < 16; k++) hn[k] = h[k] / (rs + 1e-6f);
    for (int k = 16; k < 24; k++) hn[k] = h[k] / (as + 1e-6f);
  }
  __syncthreads();
  if (t < 64) {
    float acc = bias[t];
    #pragma unroll
    for (int k = 0; k < 24; k++) acc += hn[k] * W[t * 24 + k];
    out[b * 64 + t] = acc;
  }
}

extern "C" void kernel_launch(void* const* d_in, const int* in_sizes, int n_in,
                              void* d_out, int out_size, void* d_ws, size_t ws_size,
                              hipStream_t stream) {
  const float* x    = (const float*)d_in[0];   // [64,3,512,512]
  const float* W    = (const float*)d_in[1];   // [64,24]
  const float* bias = (const float*)d_in[2];   // [64]
  float* out = (float*)d_out;                  // [64,64]

  // ws layout: partial hists | bin table | complex intermediate F
  const size_t partial_bytes = (size_t)64 * NTILE * 24 * sizeof(float);
  size_t off_bins = (partial_bytes + 255) & ~(size_t)255;
  const size_t bins_bytes = (size_t)512 * W2P;
  size_t off_F = ((off_bins + bins_bytes) + 255) & ~(size_t)255;

  float* partial = (float*)d_ws;
  unsigned char* binsNat = (unsigned char*)d_ws + off_bins;
  float2* F = (float2*)((char*)d_ws + off_F);

  const size_t per_batch = (size_t)3 * 512 * W2P * sizeof(float2);  // 3.34 MB
  size_t avail = ws_size > off_F ? ws_size - off_F : 0;
  int bpc = (int)(avail / per_batch);
  if (bpc < 1) bpc = 1;
  if (bpc > 64) bpc = 64;

  pass0_kernel<<<512, TPB, 0, stream>>>(binsNat);

  for (int b0 = 0; b0 < 64; b0 += bpc) {
    int nb = (64 - b0) < bpc ? (64 - b0) : bpc;
    pass1_kernel<<<nb * 3 * 256, TPB, 0, stream>>>(x, F, b0 * 3);
    pass2_kernel<<<nb * NTILE, TPB2, 0, stream>>>(F, binsNat, partial, b0);
  }
  pass3_kernel<<<64, TPB, 0, stream>>>(partial, W, bias, out);
}